// Round 5
// baseline (531.660 us; speedup 1.0000x reference)
//
#include <hip/hip_runtime.h>
#include <hip/hip_bf16.h>
#include <cstdint>

// Problem constants
#define BB  8
#define CH  64
#define TT  4096
#define KNN 9

#define NEG_INF (-3.402823466e38f)

// qt padded layout: 8 groups of 16 cols, each group padded to 20 floats.
#define QSTRIDE 160

// Workspace layout (float elements)
constexpr size_t OFF_QHAT = 0;                                    // [B][C][T]
constexpr size_t OFF_KHAT = (size_t)BB * CH * TT;
constexpr size_t OFF_U    = OFF_KHAT + (size_t)BB * CH * TT;      // u[B][9][T][C]
constexpr size_t OFF_CWP  = OFF_U + (size_t)BB * KNN * TT * CH;   // cwp[9][64][64]
constexpr size_t OFF_PV   = OFF_CWP + (size_t)KNN * CH * CH;      // pv[B][2][T][9]
constexpr size_t OFF_PI   = OFF_PV + (size_t)BB * 2 * TT * KNN;   // pi[B][2][T][9]
constexpr size_t OFF_IDX  = OFF_PI + (size_t)BB * 2 * TT * KNN;   // idx[B][T][9]

// ---------------------------------------------------------------------------
// Unconditional sorted-9 insert (s[0]=9th best, ascending). Provable no-op
// when w <= s[0]. Straight-line: 9 cmp + 17 cndmask + 8 med3 + 1 max.
// Reference params keep SROA intact (round-3 lesson).
// ---------------------------------------------------------------------------
__device__ __forceinline__ void insert9u(float w, int wi, float (&s)[9], int (&si)[9]) {
    bool c[9];
    #pragma unroll
    for (int k = 0; k < 9; ++k) c[k] = w > s[k];
    #pragma unroll
    for (int k = 0; k < 8; ++k) si[k] = c[k + 1] ? si[k + 1] : (c[k] ? wi : si[k]);
    si[8] = c[8] ? wi : si[8];
    #pragma unroll
    for (int k = 0; k < 8; ++k) s[k] = __builtin_amdgcn_fmed3f(s[k], s[k + 1], w);
    s[8] = fmaxf(s[8], w);
}

// scan one 16-wide acc row (branch-free streaming inserts, ascending j for
// stable tie-break: incumbent/earlier col wins on equal values).
__device__ __forceinline__ void scan16u(float (&a)[16], int jcol0, float (&s)[9], int (&si)[9]) {
    #pragma unroll
    for (int j = 0; j < 16; ++j) insert9u(a[j], jcol0 + j, s, si);
}

// merge the 8 per-lane lists of one row (8 consecutive lanes share a row).
__device__ __forceinline__ void merge8(float (&s)[9], int (&si)[9], float* pvrow, int* pirow) {
    #pragma unroll 1
    for (int m = 0; m < 9; ++m) {
        float hv = s[8]; int hi = si[8];
        #pragma unroll
        for (int d = 1; d < 8; d <<= 1) {
            float ov = __shfl_xor(hv, d);
            int   oi = __shfl_xor(hi, d);
            bool take = (ov > hv) || (ov == hv && oi < hi);
            hv = take ? ov : hv; hi = take ? oi : hi;
        }
        if (s[8] == hv && si[8] == hi) {
            pvrow[m] = hv; pirow[m] = hi;
            #pragma unroll
            for (int k = 8; k > 0; --k) { s[k] = s[k - 1]; si[k] = si[k - 1]; }
            s[0] = NEG_INF; si[0] = -1;
        }
    }
}

// ---------------------------------------------------------------------------
// K0: repack conv_w[o][cc*9+kk] -> cwp[kk][cc][o]
// ---------------------------------------------------------------------------
__global__ void repack_cw_kernel(const float* __restrict__ cw, float* __restrict__ cwp) {
    int e = blockIdx.x * blockDim.x + threadIdx.x;
    if (e >= KNN * CH * CH) return;
    int o  = e & 63;
    int cc = (e >> 6) & 63;
    int kk = e >> 12;
    cwp[e] = cw[o * (CH * KNN) + cc * KNN + kk];
}

// ---------------------------------------------------------------------------
// K1: QKV projection + L2 normalize + u-projection (unchanged, passing)
// ---------------------------------------------------------------------------
__global__ __launch_bounds__(256) void qkvu_kernel(
        const float* __restrict__ x,
        const float* __restrict__ Wq, const float* __restrict__ Wk, const float* __restrict__ Wv,
        const float* __restrict__ cwp,
        float* __restrict__ qhat, float* __restrict__ khat, float* __restrict__ u) {
    __shared__ __align__(16) float xs[CH * 64];
    __shared__ __align__(16) float vs[CH * 64];
    __shared__ __align__(16) float wl[CH * 64];
    __shared__ float pq[4 * 64], pk[4 * 64];

    const int b   = blockIdx.x >> 6;
    const int tb  = blockIdx.x & 63;
    const int tid = threadIdx.x;

    const float* xb = x + ((size_t)b * CH) * TT + tb * 64;
    #pragma unroll
    for (int m = 0; m < 16; ++m) {
        int l = tid + 256 * m;
        xs[l] = xb[(size_t)(l >> 6) * TT + (l & 63)];
    }
    __syncthreads();

    const int t = tid & 63;
    const int g = __builtin_amdgcn_readfirstlane(tid >> 6);
    const int d0 = g * 16;

    float qa[16], ka[16], va[16];
    #pragma unroll
    for (int dd = 0; dd < 16; ++dd) { qa[dd] = 0.f; ka[dd] = 0.f; va[dd] = 0.f; }

    #pragma unroll 4
    for (int c = 0; c < CH; ++c) {
        float xv = xs[c * 64 + t];
        #pragma unroll
        for (int dd = 0; dd < 16; ++dd) {
            qa[dd] = fmaf(Wq[(d0 + dd) * CH + c], xv, qa[dd]);
            ka[dd] = fmaf(Wk[(d0 + dd) * CH + c], xv, ka[dd]);
            va[dd] = fmaf(Wv[(d0 + dd) * CH + c], xv, va[dd]);
        }
    }

    float sq = 0.f, sk = 0.f;
    #pragma unroll
    for (int dd = 0; dd < 16; ++dd) { sq = fmaf(qa[dd], qa[dd], sq); sk = fmaf(ka[dd], ka[dd], sk); }
    pq[g * 64 + t] = sq;
    pk[g * 64 + t] = sk;
    __syncthreads();

    const float nq = sqrtf(pq[t] + pq[64 + t] + pq[128 + t] + pq[192 + t]);
    const float nk = sqrtf(pk[t] + pk[64 + t] + pk[128 + t] + pk[192 + t]);
    const float isq = 1.0f / fmaxf(nq, 1e-12f);
    const float isk = 1.0f / fmaxf(nk, 1e-12f);

    #pragma unroll
    for (int dd = 0; dd < 16; ++dd) {
        size_t go = ((size_t)b * CH + (d0 + dd)) * TT + tb * 64 + t;
        qhat[go] = qa[dd] * isq;
        khat[go] = ka[dd] * isk;
        vs[(d0 + dd) * 64 + t] = va[dd];
    }
    __syncthreads();

    const int to = tid & 15;
    const int tt = tid >> 4;
    for (int kk = 0; kk < KNN; ++kk) {
        #pragma unroll
        for (int m = 0; m < 16; ++m) {
            int l = tid + 256 * m;
            wl[l] = cwp[kk * (CH * CH) + l];
        }
        __syncthreads();
        float acc[4][4];
        #pragma unroll
        for (int i = 0; i < 4; ++i)
            #pragma unroll
            for (int j = 0; j < 4; ++j) acc[i][j] = 0.f;

        #pragma unroll 8
        for (int cc = 0; cc < CH; ++cc) {
            float4 wv = *(const float4*)&wl[cc * 64 + 4 * to];
            float4 vv = *(const float4*)&vs[cc * 64 + 4 * tt];
            const float wj[4] = {wv.x, wv.y, wv.z, wv.w};
            const float vi[4] = {vv.x, vv.y, vv.z, vv.w};
            #pragma unroll
            for (int i = 0; i < 4; ++i)
                #pragma unroll
                for (int j = 0; j < 4; ++j) acc[i][j] = fmaf(vi[i], wj[j], acc[i][j]);
        }
        #pragma unroll
        for (int i = 0; i < 4; ++i) {
            size_t row = (size_t)(b * KNN + kk) * TT + tb * 64 + 4 * tt + i;
            *(float4*)&u[row * CH + 4 * to] = make_float4(acc[i][0], acc[i][1], acc[i][2], acc[i][3]);
        }
        __syncthreads();
    }
}

// ---------------------------------------------------------------------------
// K2: fused sim GEMM (fp32) + branch-free register-resident top-9
//     grid 512 = b(8, XCD swizzle) x ib(32) x jslice(2); block 256 (4 waves)
//     Per-thread 4 rows x 16 cols; 128x128 tile; LDS 72 KB -> 2 blocks/CU.
//     Software-pipelined q staging: next tile's global loads issued before
//     the GEMM; ds_write after consume-barrier; scan overlaps LDS drain.
// ---------------------------------------------------------------------------
__global__ __launch_bounds__(256, 2) void sim_topk_kernel(
        const float* __restrict__ qhat, const float* __restrict__ khat,
        float* __restrict__ pv, int* __restrict__ pi) {
    __shared__ __align__(16) float kt[CH * 128];       // kt[c][i]
    __shared__ __align__(16) float qt[CH * QSTRIDE];   // qt[c][padded j]

    const int b   = blockIdx.x & 7;
    const int ib  = (blockIdx.x >> 3) & 31;
    const int js  = blockIdx.x >> 8;              // 0..1
    const int tid = threadIdx.x;

    // stage k-tile [c][128 rows], float4 coalesced (once)
    const float* kb = khat + ((size_t)b * CH) * TT + ib * 128;
    #pragma unroll
    for (int m = 0; m < 8; ++m) {
        int f = tid + 256 * m;             // float4 index
        int c = f >> 5, i4 = (f & 31) * 4;
        *(float4*)&kt[c * 128 + i4] = *(const float4*)&kb[(size_t)c * TT + i4];
    }

    const int ti = tid >> 3;   // 0..31 -> rows 4ti..4ti+3
    const int tj = tid & 7;    // col group: 16 cols at 16*tj, padded base 20*tj

    // per-thread staging slots: fixed (c, j4) per m
    const float* qb = qhat + ((size_t)b * CH) * TT + js * 2048;
    const float* qsrc[8];
    int qdst[8];
    #pragma unroll
    for (int m = 0; m < 8; ++m) {
        int f = tid + 256 * m;
        int c = f >> 5, j4 = (f & 31) * 4;
        qsrc[m] = qb + (size_t)c * TT + j4;
        qdst[m] = c * QSTRIDE + (j4 >> 4) * 20 + (j4 & 15);
    }

    float s[4][9]; int si[4][9];
    #pragma unroll
    for (int r = 0; r < 4; ++r)
        #pragma unroll
        for (int k = 0; k < 9; ++k) { s[r][k] = NEG_INF; si[r][k] = 0; }

    // prologue: stage jt=0
    float4 stg[8];
    #pragma unroll
    for (int m = 0; m < 8; ++m) stg[m] = *(const float4*)(qsrc[m]);
    #pragma unroll
    for (int m = 0; m < 8; ++m) *(float4*)&qt[qdst[m]] = stg[m];
    __syncthreads();

    for (int jt = 0; jt < 16; ++jt) {
        // issue next tile's global loads (latency hidden under GEMM)
        if (jt < 15) {
            #pragma unroll
            for (int m = 0; m < 8; ++m) stg[m] = *(const float4*)(qsrc[m] + (jt + 1) * 128);
        }

        float acc[4][16];
        #pragma unroll
        for (int r = 0; r < 4; ++r)
            #pragma unroll
            for (int j = 0; j < 16; ++j) acc[r][j] = 0.f;

        #pragma unroll 8
        for (int c = 0; c < CH; ++c) {
            float4 kv = *(const float4*)&kt[c * 128 + 4 * ti];
            float4 q0 = *(const float4*)&qt[c * QSTRIDE + 20 * tj];
            float4 q1 = *(const float4*)&qt[c * QSTRIDE + 20 * tj + 4];
            float4 q2 = *(const float4*)&qt[c * QSTRIDE + 20 * tj + 8];
            float4 q3 = *(const float4*)&qt[c * QSTRIDE + 20 * tj + 12];
            const float kr[4] = {kv.x, kv.y, kv.z, kv.w};
            const float qv[16] = {q0.x, q0.y, q0.z, q0.w, q1.x, q1.y, q1.z, q1.w,
                                  q2.x, q2.y, q2.z, q2.w, q3.x, q3.y, q3.z, q3.w};
            #pragma unroll
            for (int r = 0; r < 4; ++r)
                #pragma unroll
                for (int j = 0; j < 16; ++j)
                    acc[r][j] = fmaf(kr[r], qv[j], acc[r][j]);
        }
        __syncthreads();   // qt consumed by all waves

        // write next tile into qt; scan (register-only) overlaps the drain
        if (jt < 15) {
            #pragma unroll
            for (int m = 0; m < 8; ++m) *(float4*)&qt[qdst[m]] = stg[m];
        }

        const int j0 = js * 2048 + jt * 128 + 16 * tj;
        scan16u(acc[0], j0, s[0], si[0]);
        scan16u(acc[1], j0, s[1], si[1]);
        scan16u(acc[2], j0, s[2], si[2]);
        scan16u(acc[3], j0, s[3], si[3]);

        __syncthreads();   // qt ready for next GEMM
    }

    // per-row merge of the 8 per-lane lists (shfl over lanes sharing ti)
    const int gi = ib * 128 + 4 * ti;
    float* pv0 = pv + (((size_t)(b * 2 + js)) * TT + gi) * KNN;
    int*   pi0 = pi + (((size_t)(b * 2 + js)) * TT + gi) * KNN;
    merge8(s[0], si[0], pv0,           pi0);
    merge8(s[1], si[1], pv0 + KNN,     pi0 + KNN);
    merge8(s[2], si[2], pv0 + 2 * KNN, pi0 + 2 * KNN);
    merge8(s[3], si[3], pv0 + 3 * KNN, pi0 + 3 * KNN);
}

// ---------------------------------------------------------------------------
// K2b: merge the 2 j-slice partial lists per row -> final idx[b][t][9]
// ---------------------------------------------------------------------------
__global__ __launch_bounds__(256) void merge_slices_kernel(
        const float* __restrict__ pv, const int* __restrict__ pi,
        int* __restrict__ idxout) {
    int r = blockIdx.x * blockDim.x + threadIdx.x;
    if (r >= BB * TT) return;
    int b = r >> 12, i = r & (TT - 1);

    float s[9]; int si[9];
    #pragma unroll
    for (int k = 0; k < 9; ++k) { s[k] = NEG_INF; si[k] = 0; }

    #pragma unroll
    for (int js = 0; js < 2; ++js) {
        const float* pvr = pv + (((size_t)(b * 2 + js)) * TT + i) * KNN;
        const int*   pir = pi + (((size_t)(b * 2 + js)) * TT + i) * KNN;
        #pragma unroll
        for (int m = 0; m < 9; ++m) {
            // cross-slice: larger value wins; tie -> smaller index (stable).
            float w = pvr[m]; int wi = pir[m];
            bool c[9];
            #pragma unroll
            for (int k = 0; k < 9; ++k)
                c[k] = (w > s[k]) || (w == s[k] && wi < si[k]);
            #pragma unroll
            for (int k = 0; k < 8; ++k) si[k] = c[k + 1] ? si[k + 1] : (c[k] ? wi : si[k]);
            si[8] = c[8] ? wi : si[8];
            #pragma unroll
            for (int k = 0; k < 8; ++k) s[k] = c[k + 1] ? s[k + 1] : (c[k] ? w : s[k]);
            s[8] = c[8] ? w : s[8];
        }
    }
    int* orow = idxout + ((size_t)b * TT + i) * KNN;
    #pragma unroll
    for (int m = 0; m < 9; ++m) orow[m] = si[8 - m];
}

// ---------------------------------------------------------------------------
// K3: out[b][o][t] = conv_b[o] + sum_kk u[b][kk][idx[b][t][kk]][o]
// ---------------------------------------------------------------------------
__global__ __launch_bounds__(256) void gather_conv_kernel(
        const float* __restrict__ u, const int* __restrict__ idxin,
        const float* __restrict__ conv_b, float* __restrict__ out) {
    __shared__ int   sidx[64 * KNN];
    __shared__ float cb[CH];
    const int b   = blockIdx.x & 7;
    const int tb  = blockIdx.x >> 3;
    const int tid = threadIdx.x;

    if (tid < CH) cb[tid] = conv_b[tid];
    const int* ig = idxin + ((size_t)b * TT + tb * 64) * KNN;
    for (int l = tid; l < 64 * KNN; l += 256) sidx[l] = ig[l];
    __syncthreads();

    const int tl = tid & 63;
    const int og = tid >> 6;
    const int o0 = og * 16;

    float acc[16];
    #pragma unroll
    for (int q = 0; q < 16; ++q) acc[q] = cb[o0 + q];

    #pragma unroll
    for (int kk = 0; kk < KNN; ++kk) {
        int j = sidx[tl * KNN + kk];
        const float* up = u + (((size_t)(b * KNN + kk)) * TT + j) * CH + o0;
        #pragma unroll
        for (int q4 = 0; q4 < 4; ++q4) {
            float4 uv = *(const float4*)&up[q4 * 4];
            acc[q4 * 4 + 0] += uv.x;
            acc[q4 * 4 + 1] += uv.y;
            acc[q4 * 4 + 2] += uv.z;
            acc[q4 * 4 + 3] += uv.w;
        }
    }
    const int t = tb * 64 + tl;
    #pragma unroll
    for (int q = 0; q < 16; ++q)
        out[((size_t)b * CH + o0 + q) * TT + t] = acc[q];
}

// ---------------------------------------------------------------------------
extern "C" void kernel_launch(void* const* d_in, const int* in_sizes, int n_in,
                              void* d_out, int out_size, void* d_ws, size_t ws_size,
                              hipStream_t stream) {
    const float* x   = (const float*)d_in[0];
    const float* Wq  = (const float*)d_in[1];
    const float* Wk  = (const float*)d_in[2];
    const float* Wv  = (const float*)d_in[3];
    const float* cw  = (const float*)d_in[4];
    const float* cbp = (const float*)d_in[5];

    float* ws   = (float*)d_ws;
    float* qhat = ws + OFF_QHAT;
    float* khat = ws + OFF_KHAT;
    float* u    = ws + OFF_U;
    float* cwp  = ws + OFF_CWP;
    float* pv   = ws + OFF_PV;
    int*   pi   = (int*)(ws + OFF_PI);
    int*   idx  = (int*)(ws + OFF_IDX);
    float* out  = (float*)d_out;

    repack_cw_kernel<<<(KNN * CH * CH + 255) / 256, 256, 0, stream>>>(cw, cwp);
    qkvu_kernel<<<BB * 64, 256, 0, stream>>>(x, Wq, Wk, Wv, cwp, qhat, khat, u);
    sim_topk_kernel<<<BB * 32 * 2, 256, 0, stream>>>(qhat, khat, pv, pi);
    merge_slices_kernel<<<(BB * TT + 255) / 256, 256, 0, stream>>>(pv, pi, idx);
    gather_conv_kernel<<<BB * 64, 256, 0, stream>>>(u, idx, cbp, out);
}

// Round 6
// 505.974 us; speedup vs baseline: 1.0508x; 1.0508x over previous
//
#include <hip/hip_runtime.h>
#include <hip/hip_bf16.h>
#include <cstdint>

// Problem constants
#define BB  8
#define CH  64
#define TT  4096
#define KNN 9

#define NEG_INF (-3.402823466e38f)

// qt padded layout: 8 groups of 16 cols, each group padded to 20 floats.
#define QSTRIDE 160

typedef float v2f __attribute__((ext_vector_type(2)));

// Workspace layout (float elements)
constexpr size_t OFF_QHAT = 0;                                    // [B][C][T]
constexpr size_t OFF_KHAT = (size_t)BB * CH * TT;
constexpr size_t OFF_U    = OFF_KHAT + (size_t)BB * CH * TT;      // u[B][9][T][C]
constexpr size_t OFF_CWP  = OFF_U + (size_t)BB * KNN * TT * CH;   // cwp[9][64][64]
constexpr size_t OFF_PV   = OFF_CWP + (size_t)KNN * CH * CH;      // pv[B][2][T][9]
constexpr size_t OFF_PI   = OFF_PV + (size_t)BB * 2 * TT * KNN;   // pi[B][2][T][9]

// ---------------------------------------------------------------------------
// Unconditional sorted-9 insert (s[0]=9th best, ascending). Provable no-op
// when w <= s[0]. 9 cmp + 17 cndmask + 8 med3 + 1 max. Reference params keep
// SROA intact (round-3 lesson: runtime-indexed reg arrays -> scratch).
// ---------------------------------------------------------------------------
__device__ __forceinline__ void insert9u(float w, int wi, float (&s)[9], int (&si)[9]) {
    bool c[9];
    #pragma unroll
    for (int k = 0; k < 9; ++k) c[k] = w > s[k];
    #pragma unroll
    for (int k = 0; k < 8; ++k) si[k] = c[k + 1] ? si[k + 1] : (c[k] ? wi : si[k]);
    si[8] = c[8] ? wi : si[8];
    #pragma unroll
    for (int k = 0; k < 8; ++k) s[k] = __builtin_amdgcn_fmed3f(s[k], s[k + 1], w);
    s[8] = fmaxf(s[8], w);
}

// scan one row's 8 float2 accumulators (16 candidates), ascending j for
// stable tie-break (incumbent/earlier col wins on equal values).
__device__ __forceinline__ void scanv(v2f (&a)[8], int j0, float (&s)[9], int (&si)[9]) {
    #pragma unroll
    for (int h = 0; h < 8; ++h) {
        insert9u(a[h].x, j0 + 2 * h,     s, si);
        insert9u(a[h].y, j0 + 2 * h + 1, s, si);
    }
}

// merge the 8 per-lane lists of one row (8 consecutive lanes share a row).
__device__ __forceinline__ void merge8(float (&s)[9], int (&si)[9], float* pvrow, int* pirow) {
    #pragma unroll 1
    for (int m = 0; m < 9; ++m) {
        float hv = s[8]; int hi = si[8];
        #pragma unroll
        for (int d = 1; d < 8; d <<= 1) {
            float ov = __shfl_xor(hv, d);
            int   oi = __shfl_xor(hi, d);
            bool take = (ov > hv) || (ov == hv && oi < hi);
            hv = take ? ov : hv; hi = take ? oi : hi;
        }
        if (s[8] == hv && si[8] == hi) {
            pvrow[m] = hv; pirow[m] = hi;
            #pragma unroll
            for (int k = 8; k > 0; --k) { s[k] = s[k - 1]; si[k] = si[k - 1]; }
            s[0] = NEG_INF; si[0] = -1;
        }
    }
}

// ---------------------------------------------------------------------------
// K0: repack conv_w[o][cc*9+kk] -> cwp[kk][cc][o]
// ---------------------------------------------------------------------------
__global__ void repack_cw_kernel(const float* __restrict__ cw, float* __restrict__ cwp) {
    int e = blockIdx.x * blockDim.x + threadIdx.x;
    if (e >= KNN * CH * CH) return;
    int o  = e & 63;
    int cc = (e >> 6) & 63;
    int kk = e >> 12;
    cwp[e] = cw[o * (CH * KNN) + cc * KNN + kk];
}

// ---------------------------------------------------------------------------
// K1: QKV projection + L2 normalize + u-projection (unchanged, passing)
// ---------------------------------------------------------------------------
__global__ __launch_bounds__(256) void qkvu_kernel(
        const float* __restrict__ x,
        const float* __restrict__ Wq, const float* __restrict__ Wk, const float* __restrict__ Wv,
        const float* __restrict__ cwp,
        float* __restrict__ qhat, float* __restrict__ khat, float* __restrict__ u) {
    __shared__ __align__(16) float xs[CH * 64];
    __shared__ __align__(16) float vs[CH * 64];
    __shared__ __align__(16) float wl[CH * 64];
    __shared__ float pq[4 * 64], pk[4 * 64];

    const int b   = blockIdx.x >> 6;
    const int tb  = blockIdx.x & 63;
    const int tid = threadIdx.x;

    const float* xb = x + ((size_t)b * CH) * TT + tb * 64;
    #pragma unroll
    for (int m = 0; m < 16; ++m) {
        int l = tid + 256 * m;
        xs[l] = xb[(size_t)(l >> 6) * TT + (l & 63)];
    }
    __syncthreads();

    const int t = tid & 63;
    const int g = __builtin_amdgcn_readfirstlane(tid >> 6);
    const int d0 = g * 16;

    float qa[16], ka[16], va[16];
    #pragma unroll
    for (int dd = 0; dd < 16; ++dd) { qa[dd] = 0.f; ka[dd] = 0.f; va[dd] = 0.f; }

    #pragma unroll 4
    for (int c = 0; c < CH; ++c) {
        float xv = xs[c * 64 + t];
        #pragma unroll
        for (int dd = 0; dd < 16; ++dd) {
            qa[dd] = fmaf(Wq[(d0 + dd) * CH + c], xv, qa[dd]);
            ka[dd] = fmaf(Wk[(d0 + dd) * CH + c], xv, ka[dd]);
            va[dd] = fmaf(Wv[(d0 + dd) * CH + c], xv, va[dd]);
        }
    }

    float sq = 0.f, sk = 0.f;
    #pragma unroll
    for (int dd = 0; dd < 16; ++dd) { sq = fmaf(qa[dd], qa[dd], sq); sk = fmaf(ka[dd], ka[dd], sk); }
    pq[g * 64 + t] = sq;
    pk[g * 64 + t] = sk;
    __syncthreads();

    const float nq = sqrtf(pq[t] + pq[64 + t] + pq[128 + t] + pq[192 + t]);
    const float nk = sqrtf(pk[t] + pk[64 + t] + pk[128 + t] + pk[192 + t]);
    const float isq = 1.0f / fmaxf(nq, 1e-12f);
    const float isk = 1.0f / fmaxf(nk, 1e-12f);

    #pragma unroll
    for (int dd = 0; dd < 16; ++dd) {
        size_t go = ((size_t)b * CH + (d0 + dd)) * TT + tb * 64 + t;
        qhat[go] = qa[dd] * isq;
        khat[go] = ka[dd] * isk;
        vs[(d0 + dd) * 64 + t] = va[dd];
    }
    __syncthreads();

    const int to = tid & 15;
    const int tt = tid >> 4;
    for (int kk = 0; kk < KNN; ++kk) {
        #pragma unroll
        for (int m = 0; m < 16; ++m) {
            int l = tid + 256 * m;
            wl[l] = cwp[kk * (CH * CH) + l];
        }
        __syncthreads();
        float acc[4][4];
        #pragma unroll
        for (int i = 0; i < 4; ++i)
            #pragma unroll
            for (int j = 0; j < 4; ++j) acc[i][j] = 0.f;

        #pragma unroll 8
        for (int cc = 0; cc < CH; ++cc) {
            float4 wv = *(const float4*)&wl[cc * 64 + 4 * to];
            float4 vv = *(const float4*)&vs[cc * 64 + 4 * tt];
            const float wj[4] = {wv.x, wv.y, wv.z, wv.w};
            const float vi[4] = {vv.x, vv.y, vv.z, vv.w};
            #pragma unroll
            for (int i = 0; i < 4; ++i)
                #pragma unroll
                for (int j = 0; j < 4; ++j) acc[i][j] = fmaf(vi[i], wj[j], acc[i][j]);
        }
        #pragma unroll
        for (int i = 0; i < 4; ++i) {
            size_t row = (size_t)(b * KNN + kk) * TT + tb * 64 + 4 * tt + i;
            *(float4*)&u[row * CH + 4 * to] = make_float4(acc[i][0], acc[i][1], acc[i][2], acc[i][3]);
        }
        __syncthreads();
    }
}

// ---------------------------------------------------------------------------
// K2: fused sim GEMM (packed fp32) + branch-free register-resident top-9
//     grid 512 = b(8, XCD swizzle) x ib(32) x jslice(2); block 256 (4 waves)
//     Per-thread 4 rows x 16 cols (as 8 float2); 128x128 tile; LDS 72 KB.
//     amdgpu_waves_per_eu(2,2): LDS caps us at 2 blocks/CU anyway, so pin the
//     allocator to the 256-VGPR budget -> lists stay in arch VGPRs (no AGPR
//     accvgpr churn, the R4/R5 VALU tax).
// ---------------------------------------------------------------------------
__attribute__((amdgpu_waves_per_eu(2, 2)))
__global__ __launch_bounds__(256) void sim_topk_kernel(
        const float* __restrict__ qhat, const float* __restrict__ khat,
        float* __restrict__ pv, int* __restrict__ pi) {
    __shared__ __align__(16) float kt[CH * 128];       // kt[c][i]
    __shared__ __align__(16) float qt[CH * QSTRIDE];   // qt[c][padded j]

    const int b   = blockIdx.x & 7;
    const int ib  = (blockIdx.x >> 3) & 31;
    const int js  = blockIdx.x >> 8;              // 0..1
    const int tid = threadIdx.x;

    // stage k-tile [c][128 rows], float4 coalesced (once)
    const float* kb = khat + ((size_t)b * CH) * TT + ib * 128;
    #pragma unroll
    for (int m = 0; m < 8; ++m) {
        int f = tid + 256 * m;             // float4 index
        int c = f >> 5, i4 = (f & 31) * 4;
        *(float4*)&kt[c * 128 + i4] = *(const float4*)&kb[(size_t)c * TT + i4];
    }

    const int ti = tid >> 3;   // 0..31 -> rows 4ti..4ti+3
    const int tj = tid & 7;    // col group: 16 cols at 16*tj, padded base 20*tj

    float s[4][9]; int si[4][9];
    #pragma unroll
    for (int r = 0; r < 4; ++r)
        #pragma unroll
        for (int k = 0; k < 9; ++k) { s[r][k] = NEG_INF; si[r][k] = 0; }

    const float* qb = qhat + ((size_t)b * CH) * TT + js * 2048;

    for (int jt = 0; jt < 16; ++jt) {
        #pragma unroll
        for (int m = 0; m < 8; ++m) {
            int f = tid + 256 * m;
            int c = f >> 5, j4 = (f & 31) * 4;
            int goff = (j4 >> 4) * 20 + (j4 & 15);   // padded group layout
            *(float4*)&qt[c * QSTRIDE + goff] = *(const float4*)&qb[(size_t)c * TT + jt * 128 + j4];
        }
        __syncthreads();

        v2f acc2[4][8];
        #pragma unroll
        for (int r = 0; r < 4; ++r)
            #pragma unroll
            for (int h = 0; h < 8; ++h) acc2[r][h] = (v2f){0.f, 0.f};

        #pragma unroll 4
        for (int c = 0; c < CH; ++c) {
            float4 kv = *(const float4*)&kt[c * 128 + 4 * ti];
            float4 qA = *(const float4*)&qt[c * QSTRIDE + 20 * tj];
            float4 qB = *(const float4*)&qt[c * QSTRIDE + 20 * tj + 4];
            float4 qC = *(const float4*)&qt[c * QSTRIDE + 20 * tj + 8];
            float4 qD = *(const float4*)&qt[c * QSTRIDE + 20 * tj + 12];
            v2f q2[8];
            q2[0] = (v2f){qA.x, qA.y}; q2[1] = (v2f){qA.z, qA.w};
            q2[2] = (v2f){qB.x, qB.y}; q2[3] = (v2f){qB.z, qB.w};
            q2[4] = (v2f){qC.x, qC.y}; q2[5] = (v2f){qC.z, qC.w};
            q2[6] = (v2f){qD.x, qD.y}; q2[7] = (v2f){qD.z, qD.w};
            const float kr[4] = {kv.x, kv.y, kv.z, kv.w};
            #pragma unroll
            for (int r = 0; r < 4; ++r) {
                const v2f k2 = (v2f){kr[r], kr[r]};
                #pragma unroll
                for (int h = 0; h < 8; ++h)
                    acc2[r][h] += k2 * q2[h];     // -> v_pk_fma_f32
            }
        }
        __syncthreads();   // qt consumed; scan below is register-only

        const int j0 = js * 2048 + jt * 128 + 16 * tj;
        scanv(acc2[0], j0, s[0], si[0]);
        scanv(acc2[1], j0, s[1], si[1]);
        scanv(acc2[2], j0, s[2], si[2]);
        scanv(acc2[3], j0, s[3], si[3]);
    }

    // per-row merge of the 8 per-lane lists (shfl over lanes sharing ti)
    const int gi = ib * 128 + 4 * ti;
    float* pv0 = pv + (((size_t)(b * 2 + js)) * TT + gi) * KNN;
    int*   pi0 = pi + (((size_t)(b * 2 + js)) * TT + gi) * KNN;
    merge8(s[0], si[0], pv0,           pi0);
    merge8(s[1], si[1], pv0 + KNN,     pi0 + KNN);
    merge8(s[2], si[2], pv0 + 2 * KNN, pi0 + 2 * KNN);
    merge8(s[3], si[3], pv0 + 3 * KNN, pi0 + 3 * KNN);
}

// ---------------------------------------------------------------------------
// K3: fused slice-merge + gather + 1x1 conv
//     out[b][o][t] = conv_b[o] + sum_kk u[b][kk][idx[t][kk]][o]
//     grid 512 = b(8, XCD swizzle) x t-tile(64); block 256
// ---------------------------------------------------------------------------
__global__ __launch_bounds__(256) void gather_conv_kernel(
        const float* __restrict__ u,
        const float* __restrict__ pv, const int* __restrict__ pi,
        const float* __restrict__ conv_b, float* __restrict__ out) {
    __shared__ int   sidx[64 * KNN];
    __shared__ float cb[CH];
    const int b   = blockIdx.x & 7;
    const int tb  = blockIdx.x >> 3;
    const int tid = threadIdx.x;

    if (tid < CH) cb[tid] = conv_b[tid];

    // wave 0: merge the two 9-lists per row -> final top-9 indices
    if (tid < 64) {
        const int i = tb * 64 + tid;
        float s[9]; int si[9];
        #pragma unroll
        for (int k = 0; k < 9; ++k) { s[k] = NEG_INF; si[k] = 0; }
        #pragma unroll
        for (int js = 0; js < 2; ++js) {
            const float* pvr = pv + (((size_t)(b * 2 + js)) * TT + i) * KNN;
            const int*   pir = pi + (((size_t)(b * 2 + js)) * TT + i) * KNN;
            #pragma unroll
            for (int m = 0; m < 9; ++m) {
                float w = pvr[m]; int wi = pir[m];
                bool c[9];
                #pragma unroll
                for (int k = 0; k < 9; ++k)
                    c[k] = (w > s[k]) || (w == s[k] && wi < si[k]);
                #pragma unroll
                for (int k = 0; k < 8; ++k) si[k] = c[k + 1] ? si[k + 1] : (c[k] ? wi : si[k]);
                si[8] = c[8] ? wi : si[8];
                #pragma unroll
                for (int k = 0; k < 8; ++k) s[k] = c[k + 1] ? s[k + 1] : (c[k] ? w : s[k]);
                s[8] = c[8] ? w : s[8];
            }
        }
        #pragma unroll
        for (int m = 0; m < 9; ++m) sidx[tid * KNN + m] = si[8 - m];
    }
    __syncthreads();

    const int tl = tid & 63;
    const int og = tid >> 6;
    const int o0 = og * 16;

    float acc[16];
    #pragma unroll
    for (int q = 0; q < 16; ++q) acc[q] = cb[o0 + q];

    #pragma unroll
    for (int kk = 0; kk < KNN; ++kk) {
        int j = sidx[tl * KNN + kk];
        const float* up = u + (((size_t)(b * KNN + kk)) * TT + j) * CH + o0;
        #pragma unroll
        for (int q4 = 0; q4 < 4; ++q4) {
            float4 uv = *(const float4*)&up[q4 * 4];
            acc[q4 * 4 + 0] += uv.x;
            acc[q4 * 4 + 1] += uv.y;
            acc[q4 * 4 + 2] += uv.z;
            acc[q4 * 4 + 3] += uv.w;
        }
    }
    const int t = tb * 64 + tl;
    #pragma unroll
    for (int q = 0; q < 16; ++q)
        out[((size_t)b * CH + o0 + q) * TT + t] = acc[q];
}

// ---------------------------------------------------------------------------
extern "C" void kernel_launch(void* const* d_in, const int* in_sizes, int n_in,
                              void* d_out, int out_size, void* d_ws, size_t ws_size,
                              hipStream_t stream) {
    const float* x   = (const float*)d_in[0];
    const float* Wq  = (const float*)d_in[1];
    const float* Wk  = (const float*)d_in[2];
    const float* Wv  = (const float*)d_in[3];
    const float* cw  = (const float*)d_in[4];
    const float* cbp = (const float*)d_in[5];

    float* ws   = (float*)d_ws;
    float* qhat = ws + OFF_QHAT;
    float* khat = ws + OFF_KHAT;
    float* u    = ws + OFF_U;
    float* cwp  = ws + OFF_CWP;
    float* pv   = ws + OFF_PV;
    int*   pi   = (int*)(ws + OFF_PI);
    float* out  = (float*)d_out;

    repack_cw_kernel<<<(KNN * CH * CH + 255) / 256, 256, 0, stream>>>(cw, cwp);
    qkvu_kernel<<<BB * 64, 256, 0, stream>>>(x, Wq, Wk, Wv, cwp, qhat, khat, u);
    sim_topk_kernel<<<BB * 32 * 2, 256, 0, stream>>>(qhat, khat, pv, pi);
    gather_conv_kernel<<<BB * 64, 256, 0, stream>>>(u, pv, pi, cbp, out);
}

// Round 8
// 356.368 us; speedup vs baseline: 1.4919x; 1.4198x over previous
//
#include <hip/hip_runtime.h>
#include <hip/hip_bf16.h>
#include <cstdint>

// Problem constants
#define BB  8
#define CH  64
#define TT  4096
#define KNN 9
#define NEG_INF (-3.402823466e38f)
#define SLOTS 36          // candidate bucket per row
#define KTH   20          // collect threshold = 20th largest (margin over 9)

typedef short  s16x8 __attribute__((ext_vector_type(8)));   // 8 bf16 MFMA frag
typedef float  f32x4 __attribute__((ext_vector_type(4)));   // MFMA acc

// Workspace layout (float units)
constexpr size_t OFF_U   = 0;                                  // u f32 [B][9][T][C]
constexpr size_t OFF_QTF = (size_t)BB * KNN * TT * CH;         // 18,874,368  qhatT f32 [B][T][C]
constexpr size_t OFF_KTF = OFF_QTF + (size_t)BB * TT * CH;     // 20,971,520  khatT f32 [B][T][C]
constexpr size_t OFF_IDX = OFF_KTF + (size_t)BB * TT * CH;     // 23,068,672  idx [B][T][9] int
constexpr size_t OFF_CWP = OFF_IDX + (size_t)BB * TT * KNN;    // 23,363,584  cwp [9][64][64]
// end = 23,400,448 floats = 93.6 MB (<= proven 98.3 MB footprint)

__device__ __forceinline__ unsigned short f2bf(float f) {
    unsigned u = __float_as_uint(f);
    return (unsigned short)((u + 0x7FFFu + ((u >> 16) & 1u)) >> 16);
}

// value-only ascending top-6 via med3 chain (6 ops, no cmps/indices)
__device__ __forceinline__ void insert6(float w, float (&s)[6]) {
    #pragma unroll
    for (int k = 0; k < 5; ++k) s[k] = __builtin_amdgcn_fmed3f(s[k], s[k + 1], w);
    s[5] = fmaxf(s[5], w);
}

// exact sorted-9 insert with indices (rescore only; reference params for SROA)
__device__ __forceinline__ void insert9u(float w, int wi, float (&s)[9], int (&si)[9]) {
    bool c[9];
    #pragma unroll
    for (int k = 0; k < 9; ++k) c[k] = w > s[k];
    #pragma unroll
    for (int k = 0; k < 8; ++k) si[k] = c[k + 1] ? si[k + 1] : (c[k] ? wi : si[k]);
    si[8] = c[8] ? wi : si[8];
    #pragma unroll
    for (int k = 0; k < 8; ++k) s[k] = __builtin_amdgcn_fmed3f(s[k], s[k + 1], w);
    s[8] = fmaxf(s[8], w);
}

// pop-merge across the 16 lanes of a quad: returns the KTH-th largest of the
// union of the quad's 16 top-6 lists (destroys lists). theta <= true KTH-th
// largest of the row (union is a subset of the row's values).
__device__ __forceinline__ float popTheta(float (&s)[6], int lane) {
    float theta = NEG_INF;
    #pragma unroll 1
    for (int p = 0; p < KTH; ++p) {
        float h = s[5];
        float m = h;
        m = fmaxf(m, __shfl_xor(m, 1));
        m = fmaxf(m, __shfl_xor(m, 2));
        m = fmaxf(m, __shfl_xor(m, 4));
        m = fmaxf(m, __shfl_xor(m, 8));
        unsigned long long bal = __ballot(h == m);
        unsigned qb = (unsigned)((bal >> (lane & 48)) & 0xFFFFull);
        int owner = __ffs(qb) - 1;
        if ((lane & 15) == owner) {   // pop my head
            s[5] = s[4]; s[4] = s[3]; s[3] = s[2]; s[2] = s[1]; s[1] = s[0];
            s[0] = NEG_INF;
        }
        theta = m;
    }
    return theta;
}

// stage one 128-row q tile into LDS, fp32 -> bf16 (FULL 32-ushort half-rows —
// round-7 bug was copying only 16 of 32)
__device__ __forceinline__ void stageQ(const float* __restrict__ qbase,
                                       unsigned short* qTl, int jt, int tid) {
    int row = tid >> 1, half = tid & 1;
    const float* src = qbase + ((size_t)(jt * 128 + row)) * CH + half * 32;
    unsigned short* dst = &qTl[row * 72 + half * 32];
    #pragma unroll
    for (int p = 0; p < 4; ++p) {
        float4 f0 = *(const float4*)&src[p * 8];
        float4 f1 = *(const float4*)&src[p * 8 + 4];
        uint4 w;
        w.x = (unsigned)f2bf(f0.x) | ((unsigned)f2bf(f0.y) << 16);
        w.y = (unsigned)f2bf(f0.z) | ((unsigned)f2bf(f0.w) << 16);
        w.z = (unsigned)f2bf(f1.x) | ((unsigned)f2bf(f1.y) << 16);
        w.w = (unsigned)f2bf(f1.z) | ((unsigned)f2bf(f1.w) << 16);
        *(uint4*)&dst[p * 8] = w;
    }
}

// ---------------------------------------------------------------------------
// K0: repack conv_w[o][cc*9+kk] -> cwp[kk][cc][o]
// ---------------------------------------------------------------------------
__global__ void repack_cw_kernel(const float* __restrict__ cw, float* __restrict__ cwp) {
    int e = blockIdx.x * blockDim.x + threadIdx.x;
    if (e >= KNN * CH * CH) return;
    int o  = e & 63;
    int cc = (e >> 6) & 63;
    int kk = e >> 12;
    cwp[e] = cw[o * (CH * KNN) + cc * KNN + kk];
}

// ---------------------------------------------------------------------------
// K1: QKV + L2 normalize + u-projection (fp32) ; q/k written T-layout [T][C]
// ---------------------------------------------------------------------------
__global__ __launch_bounds__(256) void qkvu_kernel(
        const float* __restrict__ x,
        const float* __restrict__ Wq, const float* __restrict__ Wk, const float* __restrict__ Wv,
        const float* __restrict__ cwp,
        float* __restrict__ qtf, float* __restrict__ ktf,
        float* __restrict__ u) {
    __shared__ __align__(16) float xs[CH * 64];
    __shared__ __align__(16) float vs[CH * 64];
    __shared__ __align__(16) float wl[CH * 64];
    __shared__ float pq[4 * 64], pk[4 * 64];

    const int b   = blockIdx.x >> 6;
    const int tb  = blockIdx.x & 63;
    const int tid = threadIdx.x;

    const float* xb = x + ((size_t)b * CH) * TT + tb * 64;
    #pragma unroll
    for (int m = 0; m < 16; ++m) {
        int l = tid + 256 * m;
        xs[l] = xb[(size_t)(l >> 6) * TT + (l & 63)];
    }
    __syncthreads();

    const int t = tid & 63;
    const int g = __builtin_amdgcn_readfirstlane(tid >> 6);
    const int d0 = g * 16;

    float qa[16], ka[16], va[16];
    #pragma unroll
    for (int dd = 0; dd < 16; ++dd) { qa[dd] = 0.f; ka[dd] = 0.f; va[dd] = 0.f; }

    #pragma unroll 4
    for (int c = 0; c < CH; ++c) {
        float xv = xs[c * 64 + t];
        #pragma unroll
        for (int dd = 0; dd < 16; ++dd) {
            qa[dd] = fmaf(Wq[(d0 + dd) * CH + c], xv, qa[dd]);
            ka[dd] = fmaf(Wk[(d0 + dd) * CH + c], xv, ka[dd]);
            va[dd] = fmaf(Wv[(d0 + dd) * CH + c], xv, va[dd]);
        }
    }

    float sq = 0.f, sk = 0.f;
    #pragma unroll
    for (int dd = 0; dd < 16; ++dd) { sq = fmaf(qa[dd], qa[dd], sq); sk = fmaf(ka[dd], ka[dd], sk); }
    pq[g * 64 + t] = sq;
    pk[g * 64 + t] = sk;
    __syncthreads();

    const float nq = sqrtf(pq[t] + pq[64 + t] + pq[128 + t] + pq[192 + t]);
    const float nk = sqrtf(pk[t] + pk[64 + t] + pk[128 + t] + pk[192 + t]);
    const float isq = 1.0f / fmaxf(nq, 1e-12f);
    const float isk = 1.0f / fmaxf(nk, 1e-12f);

    const size_t tg = (size_t)tb * 64 + t;
    float* qf = qtf + ((size_t)b * TT + tg) * CH + d0;
    float* kf = ktf + ((size_t)b * TT + tg) * CH + d0;
    #pragma unroll
    for (int p = 0; p < 4; ++p) {
        *(float4*)&qf[p * 4] = make_float4(qa[p*4]*isq, qa[p*4+1]*isq, qa[p*4+2]*isq, qa[p*4+3]*isq);
        *(float4*)&kf[p * 4] = make_float4(ka[p*4]*isk, ka[p*4+1]*isk, ka[p*4+2]*isk, ka[p*4+3]*isk);
    }
    #pragma unroll
    for (int dd = 0; dd < 16; ++dd) vs[(d0 + dd) * 64 + t] = va[dd];
    __syncthreads();

    const int to = tid & 15;
    const int tt = tid >> 4;
    for (int kk = 0; kk < KNN; ++kk) {
        #pragma unroll
        for (int m = 0; m < 16; ++m) {
            int l = tid + 256 * m;
            wl[l] = cwp[kk * (CH * CH) + l];
        }
        __syncthreads();
        float acc[4][4];
        #pragma unroll
        for (int i = 0; i < 4; ++i)
            #pragma unroll
            for (int j = 0; j < 4; ++j) acc[i][j] = 0.f;

        #pragma unroll 8
        for (int cc = 0; cc < CH; ++cc) {
            float4 wv = *(const float4*)&wl[cc * 64 + 4 * to];
            float4 vv = *(const float4*)&vs[cc * 64 + 4 * tt];
            const float wj[4] = {wv.x, wv.y, wv.z, wv.w};
            const float vi[4] = {vv.x, vv.y, vv.z, vv.w};
            #pragma unroll
            for (int i = 0; i < 4; ++i)
                #pragma unroll
                for (int j = 0; j < 4; ++j) acc[i][j] = fmaf(vi[i], wj[j], acc[i][j]);
        }
        #pragma unroll
        for (int i = 0; i < 4; ++i) {
            size_t row = (size_t)(b * KNN + kk) * TT + tb * 64 + 4 * tt + i;
            *(float4*)&u[row * CH + 4 * to] = make_float4(acc[i][0], acc[i][1], acc[i][2], acc[i][3]);
        }
        __syncthreads();
    }
}

// ---------------------------------------------------------------------------
// K2: bf16-MFMA sim + value-only top-6 prefilter + θ-collect + exact rescore
//     grid 512 = b(8, XCD swizzle) x ib(64); block 256 (4 waves)
//     Block tile: 64 rows x 4096 cols; wave w owns rows 16w..16w+15.
//     MFMA 16x16x32: A/B n,m=lane&15, k=quad*8+j ; C/D col=lane&15,
//     row=quad*4+reg (verified layouts, m89/m120).
// ---------------------------------------------------------------------------
__global__ __launch_bounds__(256) void sim_topk_kernel(
        const float* __restrict__ qtf, const float* __restrict__ ktf,
        int* __restrict__ idxout) {
    __shared__ __align__(16) unsigned short kTl[64 * 72];    // [row][c] pad 72
    __shared__ __align__(16) unsigned short qTl[128 * 72];
    __shared__ float th[64];
    __shared__ int   cnt[64];
    __shared__ int   bkt[64 * SLOTS];
    __shared__ float wbf[64 * SLOTS];

    const int b   = blockIdx.x & 7;
    const int ib  = blockIdx.x >> 3;       // 0..63
    const int tid = threadIdx.x;
    const int lane = tid & 63;
    const int quad = lane >> 4;
    const int l15  = lane & 15;
    const int i0   = (tid >> 6) * 16;      // wave's row base (block-local)

    const float* qbase = qtf + (size_t)b * TT * CH;
    const float* kbase = ktf + (size_t)b * TT * CH;

    // stage k rows once: 64 rows x 64 c, fp32 -> bf16
    {
        int row = tid >> 2, part = tid & 3;
        const float* src = kbase + ((size_t)(ib * 64 + row)) * CH + part * 16;
        unsigned short* dst = &kTl[row * 72 + part * 16];
        #pragma unroll
        for (int p = 0; p < 2; ++p) {
            float4 f0 = *(const float4*)&src[p * 8];
            float4 f1 = *(const float4*)&src[p * 8 + 4];
            uint4 w;
            w.x = (unsigned)f2bf(f0.x) | ((unsigned)f2bf(f0.y) << 16);
            w.y = (unsigned)f2bf(f0.z) | ((unsigned)f2bf(f0.w) << 16);
            w.z = (unsigned)f2bf(f1.x) | ((unsigned)f2bf(f1.y) << 16);
            w.w = (unsigned)f2bf(f1.z) | ((unsigned)f2bf(f1.w) << 16);
            *(uint4*)&dst[p * 8] = w;
        }
    }
    if (tid < 64) cnt[tid] = 0;

    float s0[6], s1[6], s2[6], s3[6];
    #pragma unroll
    for (int k = 0; k < 6; ++k) { s0[k] = NEG_INF; s1[k] = NEG_INF; s2[k] = NEG_INF; s3[k] = NEG_INF; }

    // ------------------ PASS A: values-only top-6 ------------------
    for (int jt = 0; jt < 32; ++jt) {
        stageQ(qbase, qTl, jt, tid);
        __syncthreads();

        f32x4 acc[8];
        #pragma unroll
        for (int jj = 0; jj < 8; ++jj) acc[jj] = (f32x4){0.f, 0.f, 0.f, 0.f};
        #pragma unroll
        for (int ks = 0; ks < 2; ++ks) {
            s16x8 a = *(const s16x8*)&kTl[(i0 + l15) * 72 + ks * 32 + quad * 8];
            #pragma unroll
            for (int jj = 0; jj < 8; ++jj) {
                s16x8 bf = *(const s16x8*)&qTl[(jj * 16 + l15) * 72 + ks * 32 + quad * 8];
                acc[jj] = __builtin_amdgcn_mfma_f32_16x16x32_bf16(a, bf, acc[jj], 0, 0, 0);
            }
        }
        __syncthreads();

        #pragma unroll
        for (int jj = 0; jj < 8; ++jj) {
            insert6(acc[jj][0], s0);
            insert6(acc[jj][1], s1);
            insert6(acc[jj][2], s2);
            insert6(acc[jj][3], s3);
        }
    }

    // per-row θ = KTH-th largest of union of the quad's 16 lists
    {
        float t0v = popTheta(s0, lane);
        float t1v = popTheta(s1, lane);
        float t2v = popTheta(s2, lane);
        float t3v = popTheta(s3, lane);
        if (l15 == 0) {
            th[i0 + quad * 4 + 0] = t0v;
            th[i0 + quad * 4 + 1] = t1v;
            th[i0 + quad * 4 + 2] = t2v;
            th[i0 + quad * 4 + 3] = t3v;
        }
    }
    __syncthreads();

    const int r0 = i0 + quad * 4;
    const float th0 = th[r0], th1 = th[r0 + 1], th2 = th[r0 + 2], th3 = th[r0 + 3];

    // ------------------ PASS B: recompute (bitwise-identical) + collect -----
    for (int jt = 0; jt < 32; ++jt) {
        stageQ(qbase, qTl, jt, tid);
        __syncthreads();

        f32x4 acc[8];
        #pragma unroll
        for (int jj = 0; jj < 8; ++jj) acc[jj] = (f32x4){0.f, 0.f, 0.f, 0.f};
        #pragma unroll
        for (int ks = 0; ks < 2; ++ks) {
            s16x8 a = *(const s16x8*)&kTl[(i0 + l15) * 72 + ks * 32 + quad * 8];
            #pragma unroll
            for (int jj = 0; jj < 8; ++jj) {
                s16x8 bf = *(const s16x8*)&qTl[(jj * 16 + l15) * 72 + ks * 32 + quad * 8];
                acc[jj] = __builtin_amdgcn_mfma_f32_16x16x32_bf16(a, bf, acc[jj], 0, 0, 0);
            }
        }
        __syncthreads();

        #pragma unroll
        for (int jj = 0; jj < 8; ++jj) {
            const int j = jt * 128 + jj * 16 + l15;
            if (acc[jj][0] >= th0) { int sl = atomicAdd(&cnt[r0 + 0], 1); if (sl < SLOTS) bkt[(r0 + 0) * SLOTS + sl] = j; }
            if (acc[jj][1] >= th1) { int sl = atomicAdd(&cnt[r0 + 1], 1); if (sl < SLOTS) bkt[(r0 + 1) * SLOTS + sl] = j; }
            if (acc[jj][2] >= th2) { int sl = atomicAdd(&cnt[r0 + 2], 1); if (sl < SLOTS) bkt[(r0 + 2) * SLOTS + sl] = j; }
            if (acc[jj][3] >= th3) { int sl = atomicAdd(&cnt[r0 + 3], 1); if (sl < SLOTS) bkt[(r0 + 3) * SLOTS + sl] = j; }
        }
    }
    __syncthreads();

    // ------------------ exact fp32 rescore ------------------
    {
        int r = tid >> 2, sub = tid & 3;
        int n = min(cnt[r], SLOTS);
        const float* krow = kbase + ((size_t)(ib * 64 + r)) * CH;
        for (int m = sub; m < n; m += 4) {
            int j = bkt[r * SLOTS + m];
            const float* qrow = qbase + (size_t)j * CH;
            float w = 0.f;
            #pragma unroll
            for (int c4 = 0; c4 < 16; ++c4) {
                float4 kv = *(const float4*)&krow[c4 * 4];
                float4 qv = *(const float4*)&qrow[c4 * 4];
                w = fmaf(kv.x, qv.x, w); w = fmaf(kv.y, qv.y, w);
                w = fmaf(kv.z, qv.z, w); w = fmaf(kv.w, qv.w, w);
            }
            wbf[r * SLOTS + m] = w;
        }
    }
    __syncthreads();

    if (tid < 64) {
        int n = min(cnt[tid], SLOTS);
        float s9[9]; int si9[9];
        #pragma unroll
        for (int k = 0; k < 9; ++k) { s9[k] = NEG_INF; si9[k] = 0; }
        #pragma unroll 1
        for (int m = 0; m < n; ++m) insert9u(wbf[tid * SLOTS + m], bkt[tid * SLOTS + m], s9, si9);
        int* orow = idxout + ((size_t)b * TT + ib * 64 + tid) * KNN;
        #pragma unroll
        for (int m = 0; m < 9; ++m) orow[m] = si9[8 - m];
    }
}

// ---------------------------------------------------------------------------
// K3: out[b][o][t] = conv_b[o] + sum_kk u[b][kk][idx[t][kk]][o]  (fp32 u)
// ---------------------------------------------------------------------------
__global__ __launch_bounds__(256) void gather_conv_kernel(
        const float* __restrict__ u, const int* __restrict__ idxin,
        const float* __restrict__ conv_b, float* __restrict__ out) {
    __shared__ int   sidx[64 * KNN];
    __shared__ float cb[CH];
    const int b   = blockIdx.x & 7;
    const int tb  = blockIdx.x >> 3;
    const int tid = threadIdx.x;

    if (tid < CH) cb[tid] = conv_b[tid];
    const int* ig = idxin + ((size_t)b * TT + tb * 64) * KNN;
    for (int l = tid; l < 64 * KNN; l += 256) sidx[l] = ig[l];
    __syncthreads();

    const int tl = tid & 63;
    const int og = tid >> 6;
    const int o0 = og * 16;

    float acc[16];
    #pragma unroll
    for (int q = 0; q < 16; ++q) acc[q] = cb[o0 + q];

    #pragma unroll
    for (int kk = 0; kk < KNN; ++kk) {
        int j = sidx[tl * KNN + kk];
        const float* up = u + (((size_t)(b * KNN + kk)) * TT + j) * CH + o0;
        #pragma unroll
        for (int q4 = 0; q4 < 4; ++q4) {
            float4 uv = *(const float4*)&up[q4 * 4];
            acc[q4 * 4 + 0] += uv.x;
            acc[q4 * 4 + 1] += uv.y;
            acc[q4 * 4 + 2] += uv.z;
            acc[q4 * 4 + 3] += uv.w;
        }
    }
    const int t = tb * 64 + tl;
    #pragma unroll
    for (int q = 0; q < 16; ++q)
        out[((size_t)b * CH + o0 + q) * TT + t] = acc[q];
}

// ---------------------------------------------------------------------------
extern "C" void kernel_launch(void* const* d_in, const int* in_sizes, int n_in,
                              void* d_out, int out_size, void* d_ws, size_t ws_size,
                              hipStream_t stream) {
    const float* x   = (const float*)d_in[0];
    const float* Wq  = (const float*)d_in[1];
    const float* Wk  = (const float*)d_in[2];
    const float* Wv  = (const float*)d_in[3];
    const float* cw  = (const float*)d_in[4];
    const float* cbp = (const float*)d_in[5];

    float* ws  = (float*)d_ws;
    float* u   = ws + OFF_U;
    float* qtf = ws + OFF_QTF;
    float* ktf = ws + OFF_KTF;
    int*   idx = (int*)(ws + OFF_IDX);
    float* cwp = ws + OFF_CWP;
    float* out = (float*)d_out;

    repack_cw_kernel<<<(KNN * CH * CH + 255) / 256, 256, 0, stream>>>(cw, cwp);
    qkvu_kernel<<<BB * 64, 256, 0, stream>>>(x, Wq, Wk, Wv, cwp, qtf, ktf, u);
    sim_topk_kernel<<<BB * 64, 256, 0, stream>>>(qtf, ktf, idx);
    gather_conv_kernel<<<BB * 64, 256, 0, stream>>>(u, idx, cbp, out);
}

// Round 9
// 335.201 us; speedup vs baseline: 1.5861x; 1.0631x over previous
//
#include <hip/hip_runtime.h>
#include <hip/hip_bf16.h>
#include <cstdint>

// Problem constants
#define BB  8
#define CH  64
#define TT  4096
#define KNN 9
#define NEG_INF (-3.402823466e38f)
#define SLOTS 48          // candidate bucket per row (both halves)
#define KTH   12          // θ = 12th largest of per-half lane-union

typedef short  s16x8 __attribute__((ext_vector_type(8)));   // 8 bf16 MFMA frag
typedef float  f32x4 __attribute__((ext_vector_type(4)));   // MFMA acc

// Workspace layout (float units) — end 16,060,416 floats = 64.2 MB
constexpr size_t OFF_UB  = 0;                                  // u bf16 [B][9][T][C] ushort
constexpr size_t OFF_QTF = (size_t)BB*KNN*TT*CH/2;             //  9,437,184 qhatT f32 [B][T][C]
constexpr size_t OFF_KTF = OFF_QTF + (size_t)BB*TT*CH;         // 11,534,336 khatT f32
constexpr size_t OFF_QTB = OFF_KTF + (size_t)BB*TT*CH;         // 13,631,488 qhatT bf16 ushort
constexpr size_t OFF_KTB = OFF_QTB + (size_t)BB*TT*CH/2;       // 14,680,064 khatT bf16
constexpr size_t OFF_IDX = OFF_KTB + (size_t)BB*TT*CH/2;       // 15,728,640 idx [B][T][9]
constexpr size_t OFF_CWP = OFF_IDX + (size_t)BB*TT*KNN;        // 16,023,552 cwp [9][64][64]

__device__ __forceinline__ unsigned short f2bf(float f) {
    unsigned u = __float_as_uint(f);
    return (unsigned short)((u + 0x7FFFu + ((u >> 16) & 1u)) >> 16);
}

// value-only ascending top-4 (3 med3 + 1 max); reference params keep SROA.
__device__ __forceinline__ void insert4(float w, float (&s)[4]) {
    s[0] = __builtin_amdgcn_fmed3f(s[0], s[1], w);
    s[1] = __builtin_amdgcn_fmed3f(s[1], s[2], w);
    s[2] = __builtin_amdgcn_fmed3f(s[2], s[3], w);
    s[3] = fmaxf(s[3], w);
}

// θ = KTH-th largest of the union of the quad's 16 top-4 lists (destroys
// lists). Union ⊆ half-row ⇒ θ ≤ half-row's KTH-th largest (safe threshold).
__device__ __forceinline__ float popTheta4(float (&s)[4], int lane) {
    float theta = NEG_INF;
    #pragma unroll 1
    for (int p = 0; p < KTH; ++p) {
        float h = s[3];
        float m = h;
        m = fmaxf(m, __shfl_xor(m, 1));
        m = fmaxf(m, __shfl_xor(m, 2));
        m = fmaxf(m, __shfl_xor(m, 4));
        m = fmaxf(m, __shfl_xor(m, 8));
        unsigned long long bal = __ballot(h == m);
        unsigned qb = (unsigned)((bal >> (lane & 48)) & 0xFFFFull);
        int owner = __ffs(qb) - 1;
        if ((lane & 15) == owner) {
            s[3] = s[2]; s[2] = s[1]; s[1] = s[0]; s[0] = NEG_INF;
        }
        theta = m;
    }
    return theta;
}

// exact sorted-9 insert, value desc w/ index-asc tiebreak (final sort only)
__device__ __forceinline__ void insert9x(float w, int wi, float (&s)[9], int (&si)[9]) {
    bool c[9];
    #pragma unroll
    for (int k = 0; k < 9; ++k) c[k] = (w > s[k]) || (w == s[k] && wi < si[k]);
    #pragma unroll
    for (int k = 0; k < 8; ++k) si[k] = c[k + 1] ? si[k + 1] : (c[k] ? wi : si[k]);
    si[8] = c[8] ? wi : si[8];
    #pragma unroll
    for (int k = 0; k < 8; ++k) s[k] = c[k + 1] ? s[k + 1] : (c[k] ? w : s[k]);
    s[8] = c[8] ? w : s[8];
}

// ---------------------------------------------------------------------------
// K0: repack conv_w[o][cc*9+kk] -> cwp[kk][cc][o]
// ---------------------------------------------------------------------------
__global__ void repack_cw_kernel(const float* __restrict__ cw, float* __restrict__ cwp) {
    int e = blockIdx.x * blockDim.x + threadIdx.x;
    if (e >= KNN * CH * CH) return;
    int o  = e & 63;
    int cc = (e >> 6) & 63;
    int kk = e >> 12;
    cwp[e] = cw[o * (CH * KNN) + cc * KNN + kk];
}

// ---------------------------------------------------------------------------
// K1: QKV + L2 normalize + u-projection (u bf16) + q/k T-layout fp32 & bf16
// ---------------------------------------------------------------------------
__global__ __launch_bounds__(256) void qkvu_kernel(
        const float* __restrict__ x,
        const float* __restrict__ Wq, const float* __restrict__ Wk, const float* __restrict__ Wv,
        const float* __restrict__ cwp,
        float* __restrict__ qtf, float* __restrict__ ktf,
        unsigned short* __restrict__ qtb, unsigned short* __restrict__ ktb,
        unsigned short* __restrict__ ub) {
    __shared__ __align__(16) float xs[CH * 64];
    __shared__ __align__(16) float vs[CH * 64];
    __shared__ __align__(16) float wl[CH * 64];
    __shared__ float pq[4 * 64], pk[4 * 64];

    const int b   = blockIdx.x >> 6;
    const int tb  = blockIdx.x & 63;
    const int tid = threadIdx.x;

    const float* xb = x + ((size_t)b * CH) * TT + tb * 64;
    #pragma unroll
    for (int m = 0; m < 16; ++m) {
        int l = tid + 256 * m;
        xs[l] = xb[(size_t)(l >> 6) * TT + (l & 63)];
    }
    __syncthreads();

    const int t = tid & 63;
    const int g = __builtin_amdgcn_readfirstlane(tid >> 6);
    const int d0 = g * 16;

    float qa[16], ka[16], va[16];
    #pragma unroll
    for (int dd = 0; dd < 16; ++dd) { qa[dd] = 0.f; ka[dd] = 0.f; va[dd] = 0.f; }

    #pragma unroll 4
    for (int c = 0; c < CH; ++c) {
        float xv = xs[c * 64 + t];
        #pragma unroll
        for (int dd = 0; dd < 16; ++dd) {
            qa[dd] = fmaf(Wq[(d0 + dd) * CH + c], xv, qa[dd]);
            ka[dd] = fmaf(Wk[(d0 + dd) * CH + c], xv, ka[dd]);
            va[dd] = fmaf(Wv[(d0 + dd) * CH + c], xv, va[dd]);
        }
    }

    float sq = 0.f, sk = 0.f;
    #pragma unroll
    for (int dd = 0; dd < 16; ++dd) { sq = fmaf(qa[dd], qa[dd], sq); sk = fmaf(ka[dd], ka[dd], sk); }
    pq[g * 64 + t] = sq;
    pk[g * 64 + t] = sk;
    __syncthreads();

    const float nq = sqrtf(pq[t] + pq[64 + t] + pq[128 + t] + pq[192 + t]);
    const float nk = sqrtf(pk[t] + pk[64 + t] + pk[128 + t] + pk[192 + t]);
    const float isq = 1.0f / fmaxf(nq, 1e-12f);
    const float isk = 1.0f / fmaxf(nk, 1e-12f);

    const size_t tg = (size_t)tb * 64 + t;
    float qn[16], kn[16];
    #pragma unroll
    for (int dd = 0; dd < 16; ++dd) {
        qn[dd] = qa[dd] * isq;
        kn[dd] = ka[dd] * isk;
        vs[(d0 + dd) * 64 + t] = va[dd];
    }
    float* qf = qtf + ((size_t)b * TT + tg) * CH + d0;
    float* kf = ktf + ((size_t)b * TT + tg) * CH + d0;
    #pragma unroll
    for (int p = 0; p < 4; ++p) {
        *(float4*)&qf[p * 4] = make_float4(qn[p*4], qn[p*4+1], qn[p*4+2], qn[p*4+3]);
        *(float4*)&kf[p * 4] = make_float4(kn[p*4], kn[p*4+1], kn[p*4+2], kn[p*4+3]);
    }
    unsigned* qh = (unsigned*)(qtb + ((size_t)b * TT + tg) * CH + d0);
    unsigned* kh = (unsigned*)(ktb + ((size_t)b * TT + tg) * CH + d0);
    #pragma unroll
    for (int p = 0; p < 8; ++p) {
        qh[p] = (unsigned)f2bf(qn[2*p]) | ((unsigned)f2bf(qn[2*p+1]) << 16);
        kh[p] = (unsigned)f2bf(kn[2*p]) | ((unsigned)f2bf(kn[2*p+1]) << 16);
    }
    __syncthreads();

    const int to = tid & 15;
    const int tt = tid >> 4;
    for (int kk = 0; kk < KNN; ++kk) {
        #pragma unroll
        for (int m = 0; m < 16; ++m) {
            int l = tid + 256 * m;
            wl[l] = cwp[kk * (CH * CH) + l];
        }
        __syncthreads();
        float acc[4][4];
        #pragma unroll
        for (int i = 0; i < 4; ++i)
            #pragma unroll
            for (int j = 0; j < 4; ++j) acc[i][j] = 0.f;

        #pragma unroll 8
        for (int cc = 0; cc < CH; ++cc) {
            float4 wv = *(const float4*)&wl[cc * 64 + 4 * to];
            float4 vv = *(const float4*)&vs[cc * 64 + 4 * tt];
            const float wj[4] = {wv.x, wv.y, wv.z, wv.w};
            const float vi[4] = {vv.x, vv.y, vv.z, vv.w};
            #pragma unroll
            for (int i = 0; i < 4; ++i)
                #pragma unroll
                for (int j = 0; j < 4; ++j) acc[i][j] = fmaf(vi[i], wj[j], acc[i][j]);
        }
        #pragma unroll
        for (int i = 0; i < 4; ++i) {
            size_t row = (size_t)(b * KNN + kk) * TT + tb * 64 + 4 * tt + i;
            unsigned w0 = (unsigned)f2bf(acc[i][0]) | ((unsigned)f2bf(acc[i][1]) << 16);
            unsigned w1 = (unsigned)f2bf(acc[i][2]) | ((unsigned)f2bf(acc[i][3]) << 16);
            *(uint2*)&ub[row * CH + 4 * to] = make_uint2(w0, w1);
        }
        __syncthreads();
    }
}

// ---------------------------------------------------------------------------
// K2: BARRIER-FREE bf16-MFMA sim + top-4 prefilter + θ-collect + exact rescore
//     grid 512 = b(8, XCD swizzle: batch's 1MB q/k bf16 L2-resident) x ib(64)
//     block 256 = 4 waves, 2x2 tiling: wave (w2r,w2c) owns rows
//     [w2r*32, +32) x cols [w2c*2048, +2048). k-frags in registers; q B-frags
//     loaded straight from global (wave-coalesced 16x64B, L2-hot). No LDS in
//     the MFMA/scan loops -> no barriers -> latency hidden by ILP + waves.
// ---------------------------------------------------------------------------
__global__ __launch_bounds__(256, 2) void sim_topk_kernel(
        const unsigned short* __restrict__ qtb, const unsigned short* __restrict__ ktb,
        const float* __restrict__ qtf, const float* __restrict__ ktf,
        int* __restrict__ idxout) {
    __shared__ int   cnt[64];
    __shared__ int   bkt[64 * SLOTS];
    __shared__ float wbf[64 * SLOTS];

    const int b    = blockIdx.x & 7;
    const int ib   = blockIdx.x >> 3;      // 0..63
    const int tid  = threadIdx.x;
    const int lane = tid & 63;
    const int w    = tid >> 6;             // wave 0..3
    const int w2r  = w >> 1;               // row half
    const int w2c  = w & 1;                // col half
    const int quad = lane >> 4;
    const int l15  = lane & 15;

    if (tid < 64) cnt[tid] = 0;
    __syncthreads();

    // k A-fragments in registers: rows w2r*32 + rt*16 + l15, k = quad*8+ks*32
    const unsigned short* kb = ktb + ((size_t)b * TT + ib * 64 + w2r * 32) * CH;
    s16x8 ka[2][2];
    #pragma unroll
    for (int rt = 0; rt < 2; ++rt)
        #pragma unroll
        for (int ks = 0; ks < 2; ++ks)
            ka[rt][ks] = *(const s16x8*)(kb + (size_t)(rt * 16 + l15) * CH + ks * 32 + quad * 8);

    const unsigned short* qbB = qtb + ((size_t)b * TT + w2c * 2048) * CH;

    float s[2][4][4];
    #pragma unroll
    for (int rt = 0; rt < 2; ++rt)
        #pragma unroll
        for (int rg = 0; rg < 4; ++rg)
            #pragma unroll
            for (int k = 0; k < 4; ++k) s[rt][rg][k] = NEG_INF;

    // ------------------ PASS A: values-only top-4 (no barriers) ------------
    for (int jt = 0; jt < 16; ++jt) {
        const unsigned short* qrow = qbB + (size_t)(jt * 128 + l15) * CH + quad * 8;
        s16x8 qf[8][2];
        #pragma unroll
        for (int jj = 0; jj < 8; ++jj)
            #pragma unroll
            for (int ks = 0; ks < 2; ++ks)
                qf[jj][ks] = *(const s16x8*)(qrow + (size_t)jj * 16 * CH + ks * 32);

        f32x4 acc[2][8];
        #pragma unroll
        for (int rt = 0; rt < 2; ++rt)
            #pragma unroll
            for (int jj = 0; jj < 8; ++jj) acc[rt][jj] = (f32x4){0.f, 0.f, 0.f, 0.f};
        #pragma unroll
        for (int ks = 0; ks < 2; ++ks)
            #pragma unroll
            for (int rt = 0; rt < 2; ++rt)
                #pragma unroll
                for (int jj = 0; jj < 8; ++jj)
                    acc[rt][jj] = __builtin_amdgcn_mfma_f32_16x16x32_bf16(ka[rt][ks], qf[jj][ks], acc[rt][jj], 0, 0, 0);

        #pragma unroll
        for (int rt = 0; rt < 2; ++rt)
            #pragma unroll
            for (int jj = 0; jj < 8; ++jj) {
                insert4(acc[rt][jj][0], s[rt][0]);
                insert4(acc[rt][jj][1], s[rt][1]);
                insert4(acc[rt][jj][2], s[rt][2]);
                insert4(acc[rt][jj][3], s[rt][3]);
            }
    }

    // per-(row,half) θ — valid per half; no cross-wave merge needed
    float th[2][4];
    #pragma unroll
    for (int rt = 0; rt < 2; ++rt) {
        th[rt][0] = popTheta4(s[rt][0], lane);
        th[rt][1] = popTheta4(s[rt][1], lane);
        th[rt][2] = popTheta4(s[rt][2], lane);
        th[rt][3] = popTheta4(s[rt][3], lane);
    }

    // ------------------ PASS B: recompute (bitwise-identical) + collect ----
    for (int jt = 0; jt < 16; ++jt) {
        const unsigned short* qrow = qbB + (size_t)(jt * 128 + l15) * CH + quad * 8;
        s16x8 qf[8][2];
        #pragma unroll
        for (int jj = 0; jj < 8; ++jj)
            #pragma unroll
            for (int ks = 0; ks < 2; ++ks)
                qf[jj][ks] = *(const s16x8*)(qrow + (size_t)jj * 16 * CH + ks * 32);

        f32x4 acc[2][8];
        #pragma unroll
        for (int rt = 0; rt < 2; ++rt)
            #pragma unroll
            for (int jj = 0; jj < 8; ++jj) acc[rt][jj] = (f32x4){0.f, 0.f, 0.f, 0.f};
        #pragma unroll
        for (int ks = 0; ks < 2; ++ks)
            #pragma unroll
            for (int rt = 0; rt < 2; ++rt)
                #pragma unroll
                for (int jj = 0; jj < 8; ++jj)
                    acc[rt][jj] = __builtin_amdgcn_mfma_f32_16x16x32_bf16(ka[rt][ks], qf[jj][ks], acc[rt][jj], 0, 0, 0);

        #pragma unroll
        for (int rt = 0; rt < 2; ++rt)
            #pragma unroll
            for (int jj = 0; jj < 8; ++jj) {
                const int j = w2c * 2048 + jt * 128 + jj * 16 + l15;
                #pragma unroll
                for (int rg = 0; rg < 4; ++rg) {
                    if (acc[rt][jj][rg] >= th[rt][rg]) {
                        int rowl = w2r * 32 + rt * 16 + quad * 4 + rg;
                        int sl = atomicAdd(&cnt[rowl], 1);
                        if (sl < SLOTS) bkt[rowl * SLOTS + sl] = j;
                    }
                }
            }
    }
    __syncthreads();

    // ------------------ exact fp32 rescore (L2-hot q/k fp32) ---------------
    {
        int r = tid >> 2, sub = tid & 3;
        int n = min(cnt[r], SLOTS);
        const float* krow = ktf + ((size_t)b * TT + ib * 64 + r) * CH;
        for (int m = sub; m < n; m += 4) {
            int j = bkt[r * SLOTS + m];
            const float* qrow = qtf + ((size_t)b * TT + j) * CH;
            float wv = 0.f;
            #pragma unroll
            for (int c4 = 0; c4 < 16; ++c4) {
                float4 kv = *(const float4*)&krow[c4 * 4];
                float4 qv = *(const float4*)&qrow[c4 * 4];
                wv = fmaf(kv.x, qv.x, wv); wv = fmaf(kv.y, qv.y, wv);
                wv = fmaf(kv.z, qv.z, wv); wv = fmaf(kv.w, qv.w, wv);
            }
            wbf[r * SLOTS + m] = wv;
        }
    }
    __syncthreads();

    if (tid < 64) {
        int n = min(cnt[tid], SLOTS);
        float s9[9]; int si9[9];
        #pragma unroll
        for (int k = 0; k < 9; ++k) { s9[k] = NEG_INF; si9[k] = 0x7fffffff; }
        #pragma unroll 1
        for (int m = 0; m < n; ++m) insert9x(wbf[tid * SLOTS + m], bkt[tid * SLOTS + m], s9, si9);
        int* orow = idxout + ((size_t)b * TT + ib * 64 + tid) * KNN;
        #pragma unroll
        for (int m = 0; m < 9; ++m) orow[m] = si9[8 - m];
    }
}

// ---------------------------------------------------------------------------
// K3: out[b][o][t] = conv_b[o] + sum_kk u_bf16[b][kk][idx[t][kk]][o]
// ---------------------------------------------------------------------------
__global__ __launch_bounds__(256) void gather_conv_kernel(
        const unsigned short* __restrict__ ub, const int* __restrict__ idxin,
        const float* __restrict__ conv_b, float* __restrict__ out) {
    __shared__ int   sidx[64 * KNN];
    __shared__ float cb[CH];
    const int b   = blockIdx.x & 7;
    const int tb  = blockIdx.x >> 3;
    const int tid = threadIdx.x;

    if (tid < CH) cb[tid] = conv_b[tid];
    const int* ig = idxin + ((size_t)b * TT + tb * 64) * KNN;
    for (int l = tid; l < 64 * KNN; l += 256) sidx[l] = ig[l];
    __syncthreads();

    const int tl = tid & 63;
    const int og = tid >> 6;
    const int o0 = og * 16;

    float acc[16];
    #pragma unroll
    for (int q = 0; q < 16; ++q) acc[q] = cb[o0 + q];

    #pragma unroll
    for (int kk = 0; kk < KNN; ++kk) {
        int j = sidx[tl * KNN + kk];
        const unsigned short* up = ub + (((size_t)(b * KNN + kk)) * TT + j) * CH + o0;
        #pragma unroll
        for (int q8 = 0; q8 < 2; ++q8) {
            uint4 raw = *(const uint4*)&up[q8 * 8];
            unsigned rw[4] = {raw.x, raw.y, raw.z, raw.w};
            #pragma unroll
            for (int p = 0; p < 4; ++p) {
                acc[q8 * 8 + 2 * p]     += __uint_as_float(rw[p] << 16);
                acc[q8 * 8 + 2 * p + 1] += __uint_as_float(rw[p] & 0xFFFF0000u);
            }
        }
    }
    const int t = tb * 64 + tl;
    #pragma unroll
    for (int q = 0; q < 16; ++q)
        out[((size_t)b * CH + o0 + q) * TT + t] = acc[q];
}

// ---------------------------------------------------------------------------
extern "C" void kernel_launch(void* const* d_in, const int* in_sizes, int n_in,
                              void* d_out, int out_size, void* d_ws, size_t ws_size,
                              hipStream_t stream) {
    const float* x   = (const float*)d_in[0];
    const float* Wq  = (const float*)d_in[1];
    const float* Wk  = (const float*)d_in[2];
    const float* Wv  = (const float*)d_in[3];
    const float* cw  = (const float*)d_in[4];
    const float* cbp = (const float*)d_in[5];

    float* ws = (float*)d_ws;
    unsigned short* ub  = (unsigned short*)(ws + OFF_UB);
    float* qtf          = ws + OFF_QTF;
    float* ktf          = ws + OFF_KTF;
    unsigned short* qtb = (unsigned short*)(ws + OFF_QTB);
    unsigned short* ktb = (unsigned short*)(ws + OFF_KTB);
    int*   idx          = (int*)(ws + OFF_IDX);
    float* cwp          = ws + OFF_CWP;
    float* out          = (float*)d_out;

    repack_cw_kernel<<<(KNN * CH * CH + 255) / 256, 256, 0, stream>>>(cw, cwp);
    qkvu_kernel<<<BB * 64, 256, 0, stream>>>(x, Wq, Wk, Wv, cwp, qtf, ktf, qtb, ktb, ub);
    sim_topk_kernel<<<BB * 64, 256, 0, stream>>>(qtb, ktb, qtf, ktf, idx);
    gather_conv_kernel<<<BB * 64, 256, 0, stream>>>(ub, idx, cbp, out);
}